// Round 9
// baseline (238.587 us; speedup 1.0000x reference)
//
#include <hip/hip_runtime.h>
#include <math.h>

// Problem constants (B=4, Q=2048, KV=2048, D=512)
#define BATCH 4
#define QN    2048
#define KVN   2048
#define DN    512
#define U_TOT 15615          // int(Q * ln(KV))
#define NSEL  60             // int(8 * ln(Q))
#define NSLOT 32             // 16 j-tiles x 2 n-half waves
#define S1KS  64             // kv-splits for s1 = attn @ v (32 rows each)
#define CPART 8              // count histogram partials per batch

typedef __attribute__((ext_vector_type(8))) short bf16x8;
typedef __attribute__((ext_vector_type(4))) float f32x4;

// ---------------- helpers ----------------
__device__ __forceinline__ unsigned short f2bf(float f) {
  unsigned u = __float_as_uint(f);
  unsigned r = (u + 0x7fffu + ((u >> 16) & 1u)) >> 16;   // RNE
  return (unsigned short)r;
}
__device__ __forceinline__ float bf2f(unsigned short h) {
  return __uint_as_float(((unsigned)h) << 16);
}
__device__ __forceinline__ void gld16(const void* g, void* l) {
  __builtin_amdgcn_global_load_lds(
      (const __attribute__((address_space(1))) unsigned int*)g,
      (__attribute__((address_space(3))) unsigned int*)l, 16, 0, 0);
}

// ---------------- prep: split + count partials + zero vmean + init rowslot ------
// blocks [0,8192): bf16 hi/lo split of q,k
// blocks [8192,8224): 32 count blocks -> cntp[p][b][j] partial histograms
// block  8224: zero vmean
// blocks [8225,8257): rowslot = -1
__global__ __launch_bounds__(256) void prep_kernel(
    const float* __restrict__ q, const float* __restrict__ k,
    unsigned short* __restrict__ qhi, unsigned short* __restrict__ qlo,
    unsigned short* __restrict__ khi, unsigned short* __restrict__ klo,
    const int* __restrict__ sidx, float* __restrict__ cntp,
    float* __restrict__ vmean, int* __restrict__ rowslot)
{
  __shared__ int h[KVN];
  const int bid = blockIdx.x;
  const int t = threadIdx.x;

  if (bid < 8192) {
    const int half = bid >> 12;                       // 0 = q, 1 = k
    const int i = (bid & 4095) * 256 + t;             // float4 index
    const float* in = half ? k : q;
    unsigned short* hi = half ? khi : qhi;
    unsigned short* lo = half ? klo : qlo;
    float4 f = reinterpret_cast<const float4*>(in)[i];
    ushort4 hh, ll;
    hh.x = f2bf(f.x); ll.x = f2bf(f.x - bf2f(hh.x));
    hh.y = f2bf(f.y); ll.y = f2bf(f.y - bf2f(hh.y));
    hh.z = f2bf(f.z); ll.z = f2bf(f.z - bf2f(hh.z));
    hh.w = f2bf(f.w); ll.w = f2bf(f.w - bf2f(hh.w));
    reinterpret_cast<ushort4*>(hi)[i] = hh;
    reinterpret_cast<ushort4*>(lo)[i] = ll;
  } else if (bid < 8224) {
    const int cb = bid - 8192;      // 0..31
    const int b  = cb >> 3;
    const int p  = cb & 7;
    for (int i = t; i < KVN; i += 256) h[i] = 0;
    __syncthreads();
    const int start = p * 1952;
    const int end   = (start + 1952 < U_TOT) ? start + 1952 : U_TOT;
    for (int i = start + t; i < end; i += 256) atomicAdd(&h[sidx[b * U_TOT + i]], 1);
    __syncthreads();
    for (int i = t; i < KVN; i += 256)
      cntp[((size_t)(p * BATCH + b)) * KVN + i] = (float)h[i];
  } else if (bid == 8224) {
    for (int i = t; i < BATCH * DN; i += 256) vmean[i] = 0.f;
  } else {
    const int idx = (bid - 8225) * 256 + t;   // 0..8191
    rowslot[idx] = -1;
  }
}

// ---------------- Phase 1: dense S = q @ k^T with fused masked-max / weighted-sum ----
// XOR chunk-swizzle staging (coalesced + conflict-free), verified round 8.
__global__ __launch_bounds__(256) void s_mfma_kernel(
    const unsigned short* __restrict__ qh, const unsigned short* __restrict__ ql,
    const unsigned short* __restrict__ kh, const unsigned short* __restrict__ kl,
    const float* __restrict__ cntp, float* __restrict__ Pmax, float* __restrict__ Psum)
{
  __shared__ unsigned short Ah[128 * 32];
  __shared__ unsigned short Al[128 * 32];
  __shared__ unsigned short Bh[128 * 32];
  __shared__ unsigned short Bl[128 * 32];
  __shared__ float cnt_s[128];

  const int t = threadIdx.x;
  const int w = t >> 6;          // wave 0..3
  const int L = t & 63;
  const int mbase = (w & 1) * 64;
  const int nbase = (w >> 1) * 64;
  const int lm = L & 15;

  // XCD swizzle: xcd = bid&7 -> batch = xcd>>1, j-half = xcd&1
  const int bid = blockIdx.x;
  const int xcd = bid & 7;
  const int idx = bid >> 3;      // 0..63
  const int b   = xcd >> 1;
  const int ji  = (xcd & 1) * 8 + (idx >> 3);   // 0..15
  const int qi0 = (idx & 7) * 2;                // q-tile pair
  const int j0  = ji * 128;

  if (t < 128) {
    float c = 0.f;
#pragma unroll
    for (int p = 0; p < CPART; ++p)
      c += cntp[((size_t)(p * BATCH + b)) * KVN + j0 + t];
    cnt_s[t] = c;
  }

  // staging row/chunk (XOR-swizzled, coalesced)
  const int srow = t >> 2;                       // 0..63
  const int schk = (t & 3) ^ ((t >> 3) & 3);     // 0..3

  // fragment LDS base offsets (shorts), K-loop-invariant
  const int perm  = (L >> 4) ^ ((lm >> 1) & 3);  // c ^ s(m), 0..3
  const int abase = (mbase * 4 + lm * 4 + perm) * 8;
  const int bbase = (nbase * 4 + lm * 4 + perm) * 8;

  const size_t koff0 = ((size_t)(b * KVN) + j0 + srow) * DN + (size_t)(schk * 8);
  const size_t koff1 = koff0 + (size_t)64 * DN;

  for (int qq = 0; qq < 2; ++qq) {
    const int q0 = (qi0 + qq) * 128;
    const size_t qoff0 = ((size_t)(b * QN) + q0 + srow) * DN + (size_t)(schk * 8);
    const size_t qoff1 = qoff0 + (size_t)64 * DN;

    f32x4 acc[4][4];   // [nf][mf]
#pragma unroll
    for (int nf = 0; nf < 4; ++nf)
#pragma unroll
      for (int mf = 0; mf < 4; ++mf) {
        acc[nf][mf][0] = 0.f; acc[nf][mf][1] = 0.f;
        acc[nf][mf][2] = 0.f; acc[nf][mf][3] = 0.f;
      }

    for (int d0 = 0; d0 < DN; d0 += 32) {
      __syncthreads();   // LDS reads from previous step done
      gld16(qh + qoff0 + d0, &Ah[t * 8]);
      gld16(qh + qoff1 + d0, &Ah[(t + 256) * 8]);
      gld16(ql + qoff0 + d0, &Al[t * 8]);
      gld16(ql + qoff1 + d0, &Al[(t + 256) * 8]);
      gld16(kh + koff0 + d0, &Bh[t * 8]);
      gld16(kh + koff1 + d0, &Bh[(t + 256) * 8]);
      gld16(kl + koff0 + d0, &Bl[t * 8]);
      gld16(kl + koff1 + d0, &Bl[(t + 256) * 8]);
      __syncthreads();

      bf16x8 ah[4], al[4];
#pragma unroll
      for (int mf = 0; mf < 4; ++mf) {
        ah[mf] = *reinterpret_cast<const bf16x8*>(&Ah[abase + mf * 512]);
        al[mf] = *reinterpret_cast<const bf16x8*>(&Al[abase + mf * 512]);
      }
#pragma unroll
      for (int nf = 0; nf < 4; ++nf) {
        bf16x8 bh = *reinterpret_cast<const bf16x8*>(&Bh[bbase + nf * 512]);
        bf16x8 bl = *reinterpret_cast<const bf16x8*>(&Bl[bbase + nf * 512]);
#pragma unroll
        for (int mf = 0; mf < 4; ++mf) {
          acc[nf][mf] = __builtin_amdgcn_mfma_f32_16x16x32_bf16(ah[mf], bh, acc[nf][mf], 0, 0, 0);
          acc[nf][mf] = __builtin_amdgcn_mfma_f32_16x16x32_bf16(ah[mf], bl, acc[nf][mf], 0, 0, 0);
          acc[nf][mf] = __builtin_amdgcn_mfma_f32_16x16x32_bf16(al[mf], bh, acc[nf][mf], 0, 0, 0);
        }
      }
    }

    // fused epilogue: masked max + count-weighted sum over this j-tile
    // C/D map: j(col) = lane&15, q(row) = (lane>>4)*4 + reg  [m89-verified]
    float mx[4][4], wsm[4][4];
#pragma unroll
    for (int mf = 0; mf < 4; ++mf)
#pragma unroll
      for (int r = 0; r < 4; ++r) { mx[mf][r] = -INFINITY; wsm[mf][r] = 0.f; }

#pragma unroll
    for (int nf = 0; nf < 4; ++nf) {
      const float c = cnt_s[nbase + nf * 16 + lm];
      const bool has = (c > 0.f);
#pragma unroll
      for (int mf = 0; mf < 4; ++mf)
#pragma unroll
        for (int r = 0; r < 4; ++r) {
          const float v = acc[nf][mf][r];
          if (has) mx[mf][r] = fmaxf(mx[mf][r], v);
          wsm[mf][r] = fmaf(c, v, wsm[mf][r]);
        }
    }

    const size_t spi = (size_t)((ji * 2 + (w >> 1)) * BATCH + b);
#pragma unroll
    for (int mf = 0; mf < 4; ++mf)
#pragma unroll
      for (int r = 0; r < 4; ++r) {
        float m = mx[mf][r], s = wsm[mf][r];
#pragma unroll
        for (int o = 1; o < 16; o <<= 1) {
          m = fmaxf(m, __shfl_xor(m, o));
          s += __shfl_xor(s, o);
        }
        if (lm == 0) {
          const int qrow = q0 + mbase + mf * 16 + (L >> 4) * 4 + r;
          Pmax[spi * QN + qrow] = m;
          Psum[spi * QN + qrow] = s;
        }
      }
  }
}

// ---------------- Phase 2: fused combine + top-60 radix rank-select ---------------
// Emits compact topidx (arbitrary order) and marks rowslot (pre-initialized to -1).
__global__ __launch_bounds__(256) void select_kernel(
    const float* __restrict__ Pmax, const float* __restrict__ Psum,
    int* __restrict__ topidx, int* __restrict__ rowslot)
{
  const int b = blockIdx.x;
  const int t = threadIdx.x;
  unsigned long long key[8];
#pragma unroll
  for (int s = 0; s < 8; ++s) {
    const int qq = s * 256 + t;
    float m = -INFINITY, sm = 0.f;
#pragma unroll 4
    for (int p = 0; p < NSLOT; ++p) {
      m = fmaxf(m, Pmax[((size_t)(p * BATCH + b)) * QN + qq]);
      sm += Psum[((size_t)(p * BATCH + b)) * QN + qq];
    }
    const float M = m - sm * (1.0f / (float)U_TOT);
    unsigned u = __float_as_uint(M);
    u = (u & 0x80000000u) ? ~u : (u | 0x80000000u);   // order-preserving map
    key[s] = ((unsigned long long)u << 32) | (unsigned)(QN - qq);
  }

  __shared__ unsigned hist[256];
  __shared__ unsigned long long pref_s;
  __shared__ unsigned rank_s;
  __shared__ unsigned cnt_s;
  if (t == 0) { pref_s = 0ull; rank_s = NSEL; cnt_s = 0u; }
  __syncthreads();

  for (int level = 7; level >= 0; --level) {
    const int shift = level * 8;
    hist[t] = 0;
    __syncthreads();
    const unsigned long long pref = pref_s;
    const unsigned rank = rank_s;
#pragma unroll
    for (int s = 0; s < 8; ++s) {
      const bool match = (level == 7) || ((key[s] >> (shift + 8)) == pref);
      if (match) atomicAdd(&hist[(unsigned)((key[s] >> shift) & 255u)], 1u);
    }
    __syncthreads();
    if (t < 64) {   // wave 0: suffix-scan 256 buckets, 4 per lane
      const unsigned h0 = hist[4 * t], h1 = hist[4 * t + 1];
      const unsigned h2 = hist[4 * t + 2], h3 = hist[4 * t + 3];
      const unsigned loc = h0 + h1 + h2 + h3;
      unsigned run = loc;   // -> sum over lanes >= t
#pragma unroll
      for (int o = 1; o < 64; o <<= 1) {
        const unsigned oth = (unsigned)__shfl_down((int)run, o);
        if (t + o < 64) run += oth;
      }
      const unsigned suf = run - loc;       // cumGT past this lane's buckets
      const unsigned c3 = suf, c2 = c3 + h3, c1 = c2 + h2, c0 = c1 + h1;
      int hit = -1; unsigned cgt = 0;
      if      (c3 < rank && rank <= c3 + h3) { hit = 4 * t + 3; cgt = c3; }
      else if (c2 < rank && rank <= c2 + h2) { hit = 4 * t + 2; cgt = c2; }
      else if (c1 < rank && rank <= c1 + h1) { hit = 4 * t + 1; cgt = c1; }
      else if (c0 < rank && rank <= c0 + h0) { hit = 4 * t + 0; cgt = c0; }
      if (hit >= 0) {   // exactly one lane
        pref_s = ((level == 7) ? 0ull : (pref_s << 8)) | (unsigned long long)(unsigned)hit;
        rank_s = rank - cgt;
      }
    }
    __syncthreads();
  }

  const unsigned long long T = pref_s;   // 60th-largest key
#pragma unroll
  for (int s = 0; s < 8; ++s) {
    if (key[s] >= T) {
      const unsigned pos = atomicAdd(&cnt_s, 1u);
      const int qsel = QN - (int)(key[s] & 0xFFFFFFFFull);
      topidx[b * 64 + pos] = qsel;
      rowslot[b * QN + qsel] = (int)pos;
    }
  }
}

// ---------------- scores = q_bar @ k^T with inline q gather (raw, fp32) ----------
#define SBM 64
#define SBN 32
#define SBK 32
__global__ __launch_bounds__(256) void scores_kernel(
    const float* __restrict__ q, const int* __restrict__ topidx,
    const float* __restrict__ k, float* __restrict__ attn)
{
  __shared__ float a_s[SBK][SBM + 4];
  __shared__ float b_s[SBK][SBN + 4];
  __shared__ int tix_s[64];
  const int t  = threadIdx.x;
  const int tx = t & 7;        // 8 col-groups of 4 kv
  const int ty = t >> 3;       // 32 row-groups of 2 q
  const int kv0 = blockIdx.x * SBN;
  const int b   = blockIdx.y;
  const float* kb = k + (size_t)b * KVN * DN;

  if (t < 64) tix_s[t] = (t < NSEL) ? topidx[b * 64 + t] : 0;
  __syncthreads();

  float acc[2][4];
#pragma unroll
  for (int i = 0; i < 2; ++i)
#pragma unroll
    for (int j = 0; j < 4; ++j) acc[i][j] = 0.f;

  const int c4 = (t & 7) * 4;
  const int r0 = t >> 3;   // 0..31
  const int srow0 = tix_s[r0];
  const int srow1 = tix_s[r0 + 32];

  for (int d0 = 0; d0 < DN; d0 += SBK) {
#pragma unroll
    for (int rr = 0; rr < 2; ++rr) {
      int row = r0 + rr * 32;
      int srow = rr ? srow1 : srow0;
      float4 av = *reinterpret_cast<const float4*>(q + ((size_t)(b * QN) + srow) * DN + d0 + c4);
      a_s[c4 + 0][row] = av.x; a_s[c4 + 1][row] = av.y;
      a_s[c4 + 2][row] = av.z; a_s[c4 + 3][row] = av.w;
    }
    {
      float4 bv = *reinterpret_cast<const float4*>(kb + (size_t)(kv0 + r0) * DN + d0 + c4);
      b_s[c4 + 0][r0] = bv.x; b_s[c4 + 1][r0] = bv.y;
      b_s[c4 + 2][r0] = bv.z; b_s[c4 + 3][r0] = bv.w;
    }
    __syncthreads();
#pragma unroll
    for (int kk = 0; kk < SBK; ++kk) {
      const float a0 = a_s[kk][ty * 2];
      const float a1 = a_s[kk][ty * 2 + 1];
      float4 bv = *reinterpret_cast<const float4*>(&b_s[kk][tx * 4]);
      float bf[4] = {bv.x, bv.y, bv.z, bv.w};
#pragma unroll
      for (int j = 0; j < 4; ++j) {
        acc[0][j] = fmaf(a0, bf[j], acc[0][j]);
        acc[1][j] = fmaf(a1, bf[j], acc[1][j]);
      }
    }
    __syncthreads();
  }

#pragma unroll
  for (int i = 0; i < 2; ++i) {
    int j = ty * 2 + i;
    if (j < NSEL) {
      float4 o = make_float4(acc[i][0], acc[i][1], acc[i][2], acc[i][3]);
      *reinterpret_cast<float4*>(attn + ((size_t)(b * NSEL + j)) * KVN + kv0 + tx * 4) = o;
    }
  }
}

// ---------------- softmax over 2048 keys per selected row (shfl reductions) -------
__global__ __launch_bounds__(256) void softmax_kernel(float* __restrict__ attn)
{
  __shared__ float buf[KVN];
  __shared__ float wred[4];
  const int t = threadIdx.x;
  const int L = t & 63, wv = t >> 6;
  float* row = attn + (size_t)blockIdx.x * KVN;

  float m = -INFINITY;
  for (int i = t; i < KVN; i += 256) { float v = row[i]; buf[i] = v; m = fmaxf(m, v); }
#pragma unroll
  for (int o = 1; o < 64; o <<= 1) m = fmaxf(m, __shfl_xor(m, o));
  if (L == 0) wred[wv] = m;
  __syncthreads();
  m = fmaxf(fmaxf(wred[0], wred[1]), fmaxf(wred[2], wred[3]));

  const float sc = 0.022097086912079608f;   // 1/sqrt(2048)
  float s = 0.f;
  for (int i = t; i < KVN; i += 256) { float e = __expf((buf[i] - m) * sc); buf[i] = e; s += e; }
#pragma unroll
  for (int o = 1; o < 64; o <<= 1) s += __shfl_xor(s, o);
  __syncthreads();   // wred reuse
  if (L == 0) wred[wv] = s;
  __syncthreads();
  const float inv = 1.f / (wred[0] + wred[1] + wred[2] + wred[3]);
  for (int i = t; i < KVN; i += 256) row[i] = buf[i] * inv;
}

// ---------------- s1 partials = attn @ v + atomic v-column sums ------------------
// grid (2 d-halves, BATCH, S1KS=64 splits of 32 kv rows); block 256 = 64 dv4 x 4 jg.
__global__ __launch_bounds__(256) void s1_partial_kernel(
    const float* __restrict__ attn, const float* __restrict__ v,
    float* __restrict__ part, float* __restrict__ vmean)
{
  __shared__ float a_s[32][61];     // [kv-local][j], stride 61 odd
  const int t    = threadIdx.x;
  const int dv4  = t & 63;          // float4 column within the d-half
  const int jg   = t >> 6;          // 0..3 -> j in [jg*15, jg*15+15)
  const int dh   = blockIdx.x;      // d-half: 0 or 1
  const int b    = blockIdx.y;
  const int ks   = blockIdx.z;      // kv split
  const int kv0  = ks * 32;
  const int dbase = dh * 256 + dv4 * 4;

  // stage attn tile: 60 j x 32 kv, coalesced along kv
  for (int x = t; x < NSEL * 32; x += 256) {
    const int j = x >> 5, kk = x & 31;
    a_s[kk][j] = attn[((size_t)(b * NSEL + j)) * KVN + kv0 + kk];
  }
  __syncthreads();

  f32x4 acc[15];
#pragma unroll
  for (int i = 0; i < 15; ++i) { acc[i][0] = 0.f; acc[i][1] = 0.f; acc[i][2] = 0.f; acc[i][3] = 0.f; }
  f32x4 vsum; vsum[0] = 0.f; vsum[1] = 0.f; vsum[2] = 0.f; vsum[3] = 0.f;

  const float* vb = v + ((size_t)b * KVN + kv0) * DN + dbase;
#pragma unroll 8
  for (int kk = 0; kk < 32; ++kk) {
    const f32x4 vv = *reinterpret_cast<const f32x4*>(vb + (size_t)kk * DN);
    if (jg == 0) { vsum[0] += vv[0]; vsum[1] += vv[1]; vsum[2] += vv[2]; vsum[3] += vv[3]; }
#pragma unroll
    for (int jj = 0; jj < 15; ++jj) {
      const float a = a_s[kk][jg * 15 + jj];   // wave-uniform broadcast
      acc[jj][0] = fmaf(a, vv[0], acc[jj][0]);
      acc[jj][1] = fmaf(a, vv[1], acc[jj][1]);
      acc[jj][2] = fmaf(a, vv[2], acc[jj][2]);
      acc[jj][3] = fmaf(a, vv[3], acc[jj][3]);
    }
  }

#pragma unroll
  for (int jj = 0; jj < 15; ++jj) {
    const int j = jg * 15 + jj;
    *reinterpret_cast<f32x4*>(
        part + ((size_t)((ks * BATCH + b) * NSEL) + j) * DN + dbase) = acc[jj];
  }
  if (jg == 0) {
    float* vm = vmean + (size_t)b * DN + dbase;
    atomicAdd(vm + 0, vsum[0]);
    atomicAdd(vm + 1, vsum[1]);
    atomicAdd(vm + 2, vsum[2]);
    atomicAdd(vm + 3, vsum[3]);
  }
}

// ---------------- output: v-mean fill + s1 scatter in one pass ----------------
__global__ __launch_bounds__(256) void out_kernel(
    const float* __restrict__ part, const float* __restrict__ vmean,
    const int* __restrict__ rowslot, float* __restrict__ out)
{
  const int gid = blockIdx.x * 256 + threadIdx.x;   // float4 index, 0..1048575
  const int d4 = gid & 127;
  const int qq = (gid >> 7) & (QN - 1);
  const int b  = gid >> 18;                          // QN*DN/4 = 2^18
  const int slot = rowslot[b * QN + qq];
  f32x4 o;
  if (slot >= 0) {
    o[0] = 0.f; o[1] = 0.f; o[2] = 0.f; o[3] = 0.f;
    for (int ks = 0; ks < S1KS; ++ks) {
      const f32x4 p = reinterpret_cast<const f32x4*>(part)[
          ((size_t)((ks * BATCH + b) * NSEL) + slot) * (DN / 4) + d4];
      o[0] += p[0]; o[1] += p[1]; o[2] += p[2]; o[3] += p[3];
    }
  } else {
    const f32x4 vm = reinterpret_cast<const f32x4*>(vmean)[b * (DN / 4) + d4];
    const float sc = 1.0f / (float)KVN;
    o[0] = vm[0] * sc; o[1] = vm[1] * sc; o[2] = vm[2] * sc; o[3] = vm[3] * sc;
  }
  reinterpret_cast<f32x4*>(out)[gid] = o;
}

// ---------------- launcher ----------------
extern "C" void kernel_launch(void* const* d_in, const int* in_sizes, int n_in,
                              void* d_out, int out_size, void* d_ws, size_t ws_size,
                              hipStream_t stream) {
  const float* q    = (const float*)d_in[0];
  const float* k    = (const float*)d_in[1];
  const float* v    = (const float*)d_in[2];
  const int*   sidx = (const int*)d_in[3];
  float* out = (float*)d_out;
  char*  W   = (char*)d_ws;

  // region A [0, 32 MB): bf16 splits (dead after s_mfma_kernel)
  const size_t NEL = (size_t)BATCH * QN * DN;   // 4,194,304
  unsigned short* qh = (unsigned short*)W;
  unsigned short* ql = qh + NEL;
  unsigned short* kh = ql + NEL;
  unsigned short* kl = kh + NEL;

  // post-phase-1 buffers aliased into region A (splits dead by then)
  float* attn  = (float*)W;                  // 1.875 MB
  float* part  = (float*)(W + 2097152);      // 64*4*60*512*4 = 31.46 MB -> ends 33.55 MB
  float* vmean = (float*)(W + 34078720);     // 8 KB (outside region A; zeroed in prep)

  // region B at +36 MB: live across phases
  char* W2 = W + 37748736;
  float* cntp    = (float*)W2;                          // 8*4*2048*4 = 256 KB
  float* Pmax    = (float*)(W2 + 262144);               // 1 MB
  float* Psum    = (float*)(W2 + 262144 + 1048576);     // 1 MB
  int*   topidx  = (int*)(W2 + 262144 + 2097152);               // 1 KB (pad 4 KB)
  int*   rowslot = (int*)(W2 + 262144 + 2097152 + 4096);        // 32 KB
  // ends ~38.4 MB; ws >= 39.6 MB proven in round 2

  prep_kernel<<<dim3(8257), 256, 0, stream>>>(q, k, qh, ql, kh, kl, sidx, cntp, vmean, rowslot);
  s_mfma_kernel<<<dim3(512), 256, 0, stream>>>(qh, ql, kh, kl, cntp, Pmax, Psum);
  select_kernel<<<dim3(BATCH), 256, 0, stream>>>(Pmax, Psum, topidx, rowslot);
  scores_kernel<<<dim3(KVN / SBN, BATCH), 256, 0, stream>>>(q, topidx, k, attn);
  softmax_kernel<<<dim3(BATCH * NSEL), 256, 0, stream>>>(attn);
  s1_partial_kernel<<<dim3(2, BATCH, S1KS), 256, 0, stream>>>(attn, v, part, vmean);
  out_kernel<<<dim3(4096), 256, 0, stream>>>(part, vmean, rowslot, out);
}